// Round 9
// baseline (623.108 us; speedup 1.0000x reference)
//
#include <hip/hip_runtime.h>

// Problem dims
#define NS 64      // batch
#define TT 256     // caption length
#define TS 255     // RNN timesteps (T-1)
#define VV 10000   // vocab
#define DF 1280    // feature dim
#define WD 256     // word-embed dim
#define HD 512     // hidden dim
#define RTOT (TS*NS)   // 16320 output rows (r = t*64 + n)
#define RPAD 16384     // padded rows for hs

// 2*log2(e): tanh(x) = (e^{2x}-1)/(e^{2x}+1), e^{2x} = exp2(x * 2log2e)
#define TANH_SCALE 2.8853900817779268f
#define LOG2E 1.4426950408889634f

typedef __attribute__((ext_vector_type(4))) float f32x4;
typedef __attribute__((ext_vector_type(8))) short s16x8;
typedef __attribute__((ext_vector_type(4))) unsigned int u32x4;
typedef __attribute__((ext_vector_type(8))) int i32x8;

__device__ __forceinline__ unsigned short f2bf(float f){
  unsigned u; __builtin_memcpy(&u, &f, 4);
  u += 0x7FFFu + ((u >> 16) & 1u);            // RNE
  return (unsigned short)(u >> 16);
}
__device__ __forceinline__ float bf2f(unsigned short h){
  unsigned u = ((unsigned)h) << 16; float f; __builtin_memcpy(&f, &u, 4); return f;
}
__device__ __forceinline__ unsigned char f2fp8(float f){
  int p = __builtin_amdgcn_cvt_pk_fp8_f32(f, f, 0, false);  // OCP e4m3
  return (unsigned char)(p & 0xFF);
}
__device__ __forceinline__ float dot4_fp8(unsigned int a, unsigned int b){
  float d;
  d  = __builtin_amdgcn_cvt_f32_fp8(a, 0) * __builtin_amdgcn_cvt_f32_fp8(b, 0);
  d += __builtin_amdgcn_cvt_f32_fp8(a, 1) * __builtin_amdgcn_cvt_f32_fp8(b, 1);
  d += __builtin_amdgcn_cvt_f32_fp8(a, 2) * __builtin_amdgcn_cvt_f32_fp8(b, 2);
  d += __builtin_amdgcn_cvt_f32_fp8(a, 3) * __builtin_amdgcn_cvt_f32_fp8(b, 3);
  return d;
}
// MX-scaled MFMA, fp8 x fp8, unit scales -> exact fp8 GEMM at 2x rate (verified, absmax 0.0).
// LEDGER of k_rnn findings:
//  - trans ops (exp2/rcp) ~4-5x a VALU op; polynomial tanh is a wash (r4).
//  - compiler STREAMS MFMA operand arrays from L2 every step (VGPR 56/92 twice); asm "+v"
//    tuple pin => scratch spill, 2.4x regression (r7). Do NOT pin tuples.
//  - bound: Wh re-stream 256KB/block/step at ~128B/cyc L2 port ~ 2048cyc ~ measured step.
//  - r9: split Wh across L2 port AND LDS port (96KB LDS-resident, 160KB streamed).
__device__ __forceinline__ i32x8 cat8(u32x4 lo, u32x4 hi){
  i32x8 r;
  r[0]=(int)lo[0]; r[1]=(int)lo[1]; r[2]=(int)lo[2]; r[3]=(int)lo[3];
  r[4]=(int)hi[0]; r[5]=(int)hi[1]; r[6]=(int)hi[2]; r[7]=(int)hi[3];
  return r;
}
__device__ __forceinline__ f32x4 mfma128(i32x8 a, i32x8 b, f32x4 c){
  return __builtin_amdgcn_mfma_scale_f32_16x16x128_f8f6f4(a, b, c, 0, 0, 0, 127, 0, 127);
}

// ---------------- fused K0: all weight/input conversions in ONE kernel.
// block ranges: [0,640) W_proj transpose | [640,768) Wx transpose | [768,1792) WhS (pre-scaled)
// [1792,6800) W_out transpose fp8 | [6800,6840) feat cvt x8 | [6840,8090) Wembb cvt x8
__device__ __forceinline__ void transpose_cvt_blk(const float* __restrict__ src,
    unsigned char* __restrict__ dst, int R, int C, int bx, int by, int fp8, int tid){
  __shared__ float tile[32][33];
  int r0 = bx*32, c0 = by*32;
  int tr = tid >> 5, tc = tid & 31;
  #pragma unroll
  for(int p=0;p<4;p++){
    int r = r0 + tr + p*8, c = c0 + tc;
    tile[tr + p*8][tc] = (r < R && c < C) ? src[r*C + c] : 0.f;
  }
  __syncthreads();
  #pragma unroll
  for(int p=0;p<4;p++){
    int oc = c0 + tr + p*8;
    int orow = r0 + tc;
    if(oc < C && orow < R){
      float v = tile[tc][tr + p*8];
      if(fp8) dst[oc*R + orow] = f2fp8(v);
      else ((unsigned short*)dst)[oc*R + orow] = f2bf(v);
    }
  }
}

__global__ __launch_bounds__(256) void k_conv(const float* __restrict__ W_proj,
    const float* __restrict__ Wx, const float* __restrict__ Wh,
    const float* __restrict__ W_out, const float* __restrict__ feat,
    const float* __restrict__ W_embed,
    unsigned short* __restrict__ WprojT, unsigned short* __restrict__ WxT,
    unsigned char* __restrict__ Wh8S, unsigned char* __restrict__ WoutT,
    unsigned short* __restrict__ featb, unsigned short* __restrict__ Wembb,
    float* __restrict__ out0){
  int b = blockIdx.x, tid = threadIdx.x;
  if(b == 0 && tid == 0) out0[0] = 0.f;       // zero loss accumulator (stream-ordered)
  if(b < 640){
    transpose_cvt_blk(W_proj, (unsigned char*)WprojT, 1280, 512, b%40, b/40, 0, tid);
  } else if(b < 768){
    int bb = b - 640;
    transpose_cvt_blk(Wx, (unsigned char*)WxT, 256, 512, bb%8, bb/8, 0, tid);
  } else if(b < 1792){
    int i = (b-768)*256 + tid;                 // Wh -> wave-order K=128-frag fp8, pre-scaled by 2log2e
    int blk = i>>11;
    int w = blk>>4, ct = (blk>>2)&3, kq = blk&3;
    int lane = (i>>5)&63, ib = i&31;
    int q = lane>>4, rrr = lane&15;
    int k = kq*128 + q*32 + ib;
    int j = w*64 + ct*16 + rrr;
    Wh8S[i] = f2fp8(Wh[k*HD + j] * TANH_SCALE);
  } else if(b < 6800){
    int bb = b - 1792;
    transpose_cvt_blk(W_out, WoutT, 512, 10000, bb%16, bb/16, 1, tid);
  } else if(b < 6840){
    int i = ((b-6800)*256 + tid)*8;            // 64*1280 = 40*2048
    f32x4 v0 = *(const f32x4*)(feat + i);
    f32x4 v1 = *(const f32x4*)(feat + i + 4);
    s16x8 o;
    #pragma unroll
    for(int j=0;j<4;j++){ o[j] = (short)f2bf(v0[j]); o[j+4] = (short)f2bf(v1[j]); }
    *(s16x8*)(featb + i) = o;
  } else {
    int i = ((b-6840)*256 + tid)*8;            // 10000*256 = 1250*2048
    f32x4 v0 = *(const f32x4*)(W_embed + i);
    f32x4 v1 = *(const f32x4*)(W_embed + i + 4);
    s16x8 o;
    #pragma unroll
    for(int j=0;j<4;j++){ o[j] = (short)f2bf(v0[j]); o[j+4] = (short)f2bf(v1[j]); }
    *(s16x8*)(Wembb + i) = o;
  }
}

// ---------------- K1: h0 = feat @ W_proj + b_proj  -> bf16 [64][512]
__global__ __launch_bounds__(256) void k_h0(const unsigned short* __restrict__ featb,
    const unsigned short* __restrict__ WprojT, const float* __restrict__ b_proj,
    unsigned short* __restrict__ h0b){
  __shared__ unsigned short Al[64*264];
  __shared__ unsigned short Bl[64*264];
  int tid = threadIdx.x, cb = blockIdx.x;
  int w = tid>>6, lane = tid&63, q = lane>>4, rr = lane&15;
  f32x4 acc[4];
  #pragma unroll
  for(int i=0;i<4;i++){ acc[i][0]=0.f; acc[i][1]=0.f; acc[i][2]=0.f; acc[i][3]=0.f; }
  for(int kb=0; kb<5; kb++){
    {
      int row = tid >> 2, part = tid & 3;
      const u32x4* s = (const u32x4*)(featb + row*DF + kb*256 + part*64);
      u32x4* d = (u32x4*)(Al + row*264 + part*64);
      #pragma unroll
      for(int i=0;i<8;i++) d[i] = s[i];
    }
    {
      int row = tid >> 2, part = tid & 3;
      int j = cb*64 + row;
      const u32x4* s = (const u32x4*)(WprojT + j*DF + kb*256 + part*64);
      u32x4* d = (u32x4*)(Bl + row*264 + part*64);
      #pragma unroll
      for(int i=0;i<8;i++) d[i] = s[i];
    }
    __syncthreads();
    #pragma unroll
    for(int kc=0;kc<8;kc++){
      s16x8 a = *(const s16x8*)(Al + (w*16 + rr)*264 + kc*32 + q*8);
      #pragma unroll
      for(int tc=0;tc<4;tc++){
        s16x8 bb = *(const s16x8*)(Bl + (tc*16 + rr)*264 + kc*32 + q*8);
        acc[tc] = __builtin_amdgcn_mfma_f32_16x16x32_bf16(a, bb, acc[tc], 0, 0, 0);
      }
    }
    __syncthreads();
  }
  #pragma unroll
  for(int tc=0;tc<4;tc++){
    #pragma unroll
    for(int reg=0;reg<4;reg++){
      int n = w*16 + q*4 + reg;
      int j = cb*64 + tc*16 + rr;
      h0b[n*HD + j] = f2bf(acc[tc][reg] + b_proj[j]);
    }
  }
}

// ---------------- K2: (xW + b) * 2log2e -> xWk, SWAPPED-K3 layout (pre-scaled for exp2).
__global__ __launch_bounds__(256) void k_xw(const unsigned short* __restrict__ Wembb,
    const unsigned short* __restrict__ WxT, const float* __restrict__ bvec,
    const int* __restrict__ captions, unsigned short* __restrict__ xWk){
  __shared__ unsigned short Al[64*264];
  __shared__ unsigned short Bl[64*264];
  int tid = threadIdx.x, cb = blockIdx.x, t = blockIdx.y;
  int w = tid>>6, lane = tid&63, q = lane>>4, rr = lane&15;
  {
    int row = tid >> 2, part = tid & 3;
    int idx = captions[row*TT + t];
    const u32x4* s = (const u32x4*)(Wembb + idx*WD + part*64);
    u32x4* d = (u32x4*)(Al + row*264 + part*64);
    #pragma unroll
    for(int i=0;i<8;i++) d[i] = s[i];
  }
  {
    int row = tid >> 2, part = tid & 3;
    int j = cb*64 + row;
    const u32x4* s = (const u32x4*)(WxT + j*WD + part*64);
    u32x4* d = (u32x4*)(Bl + row*264 + part*64);
    #pragma unroll
    for(int i=0;i<8;i++) d[i] = s[i];
  }
  __syncthreads();
  f32x4 acc[4];
  #pragma unroll
  for(int i=0;i<4;i++){ acc[i][0]=0.f; acc[i][1]=0.f; acc[i][2]=0.f; acc[i][3]=0.f; }
  #pragma unroll
  for(int kc=0;kc<8;kc++){
    s16x8 a = *(const s16x8*)(Al + (w*16 + rr)*264 + kc*32 + q*8);
    #pragma unroll
    for(int tc=0;tc<4;tc++){
      s16x8 bb = *(const s16x8*)(Bl + (tc*16 + rr)*264 + kc*32 + q*8);
      acc[tc] = __builtin_amdgcn_mfma_f32_16x16x32_bf16(a, bb, acc[tc], 0, 0, 0);
    }
  }
  __syncthreads();                              // Al/Bl reads done; reuse Al as staging
  unsigned short* sx = (unsigned short*)Al;     // [4 chunks][1024] u16
  #pragma unroll
  for(int tc=0;tc<4;tc++){
    int j = cb*64 + tc*16 + rr;
    float bo = bvec[j];
    #pragma unroll
    for(int reg=0;reg<4;reg++)
      sx[w*1024 + (rr>>2)*256 + (q*4+reg)*16 + tc*4 + (rr&3)]
        = f2bf((acc[tc][reg] + bo) * TANH_SCALE);
  }
  __syncthreads();
  {
    int o = tid*16;                             // u16 units, 0..4095
    int blk = o >> 10, inner = o & 1023;
    unsigned short* dst = xWk + (((size_t)t*4 + blk)*8 + cb)*1024 + inner;
    const u32x4* s = (const u32x4*)(sx + o);
    *(u32x4*)(dst)     = s[0];
    *(u32x4*)(dst + 8) = s[1];
  }
}

// ---------------- K3: RNN scan — round-5 8-wave body + r9 TWO-PORT Wh split.
// Per wave: tuples m=0..5 of Wh live in LDS (loaded once, two-plane stride-16 layout so
// ds_read_b128 is bank-uniform); tuples m=6..15 stream from L2 per step (compiler does
// this anyway). Per-step traffic: LDS 64(af)+96(wb)KB ~ 1300cyc || L2 160KB ~ 1250cyc
// || MFMA 1107cyc — balanced, vs the old single-port 256KB/2000cyc L2 bound.
__global__ __launch_bounds__(512, 2) void k_rnn(const unsigned short* __restrict__ h0b,
    const unsigned char* __restrict__ Wh8S, const unsigned short* __restrict__ xWk,
    unsigned char* __restrict__ hs8){
  __shared__ unsigned char whl[98304];         // 8 waves x 6 tuples x 2KB (two 1KB planes)
  __shared__ unsigned char hbuf[2][16*560];    // fp8 h, [n][j] stride 560
  int tid = threadIdx.x, w = tid>>6, lane = tid&63, q = lane>>4, rr = lane&15;
  int n0 = blockIdx.x * 16;
  int j0 = w * 64;
  // LDS-resident Wh tuples (m=0..5): plane0 = bytes 0..15, plane1 = bytes 16..31
  #pragma unroll
  for(int m=0;m<6;m++){
    const unsigned char* src = Wh8S + (size_t)(w*16 + m)*2048 + lane*32;
    *(u32x4*)(whl + (w*6+m)*2048 + lane*16)        = *(const u32x4*)(src);
    *(u32x4*)(whl + (w*6+m)*2048 + 1024 + lane*16) = *(const u32x4*)(src + 16);
  }
  // streamed Wh tuples (m=6..15)
  i32x8 wb[10];
  #pragma unroll
  for(int m=6;m<16;m++)
    wb[m-6] = *(const i32x8*)(Wh8S + (size_t)(w*16 + m)*2048 + lane*32);
  {
    int s = tid>>5, c0 = (tid&31)*16;
    #pragma unroll
    for(int i=0;i<16;i++)
      hbuf[0][s*560 + c0 + i] = f2fp8(bf2f(h0b[(n0+s)*HD + c0 + i]));
  }
  __syncthreads();
  int scp = tid>>5, scc = (tid&31)*16;
  const unsigned short* xp = xWk + (((size_t)blockIdx.x)*8 + w)*1024 + q*256 + rr*16;
  unsigned short xs[16];
  *(u32x4*)(xs)   = *(const u32x4*)(xp);
  *(u32x4*)(xs+8) = *(const u32x4*)(xp+8);
  for(int t=0; t<TS; t++){
    const unsigned char* hb = hbuf[t&1];
    unsigned char*       hn = hbuf[(t&1)^1];
    if(t)
      *(u32x4*)(hs8 + (size_t)((t-1)*NS + n0 + scp)*HD + scc) = *(const u32x4*)(hb + scp*560 + scc);
    f32x4 acc[4];                               // C-operand = pre-scaled xW (swapped layout)
    #pragma unroll
    for(int ct=0;ct<4;ct++)
      #pragma unroll
      for(int reg=0;reg<4;reg++)
        acc[ct][reg] = bf2f(xs[ct*4+reg]);
    unsigned short xn[16];                      // prefetch next step's xW
    *(u32x4*)(xn)   = *(const u32x4*)(xp + 32768);
    *(u32x4*)(xn+8) = *(const u32x4*)(xp + 32768 + 8);
    i32x8 af[4];
    #pragma unroll
    for(int kq=0;kq<4;kq++)
      af[kq] = *(const i32x8*)(hb + rr*560 + kq*128 + q*32);
    #pragma unroll
    for(int ct=0;ct<4;ct++)
      #pragma unroll
      for(int kq=0;kq<4;kq++){
        const int m = ct*4 + kq;
        i32x8 a;
        if(m < 6){
          u32x4 lo = *(const u32x4*)(whl + (w*6+m)*2048 + lane*16);
          u32x4 hi = *(const u32x4*)(whl + (w*6+m)*2048 + 1024 + lane*16);
          a = cat8(lo, hi);
        } else {
          a = wb[m-6];
        }
        acc[ct] = mfma128(a, af[kq], acc[ct]);  // SWAPPED: out = (h*Wh)^T
      }
    #pragma unroll
    for(int ct=0;ct<4;ct++){
      float h[4];
      #pragma unroll
      for(int reg=0;reg<4;reg++){
        float e2 = __builtin_amdgcn_exp2f(acc[ct][reg]);              // acc pre-scaled by 2log2e
        h[reg] = __builtin_fmaf(-2.f, __builtin_amdgcn_rcpf(e2 + 1.f), 1.f);  // tanh
      }
      int pk = __builtin_amdgcn_cvt_pk_fp8_f32(h[0], h[1], 0, false);
      pk     = __builtin_amdgcn_cvt_pk_fp8_f32(h[2], h[3], pk, true);
      *(unsigned int*)(hn + rr*560 + j0 + ct*16 + q*4) = (unsigned)pk;
    }
    __syncthreads();
    xp += 32768;
    *(u32x4*)(xs)   = *(u32x4*)(xn);
    *(u32x4*)(xs+8) = *(u32x4*)(xn+8);
  }
  *(u32x4*)(hs8 + (size_t)((TS-1)*NS + n0 + scp)*HD + scc) = *(const u32x4*)(hbuf[TS&1] + scp*560 + scc);
}

// ---------------- K4: fused scores GEMM + sumexp partials — EXACT round-5 proven config
// (256 thr, dim3(4,128)). r8's 512-thr/256-row variant broke af residency (VGPR capped
// at 128 = af size => spill; 40ms anomalous profiled dispatch). FROZEN.
__global__ __launch_bounds__(256, 2) void k_scores(const unsigned char* __restrict__ hs8,
    const unsigned char* __restrict__ WoutT, const float* __restrict__ b_out,
    float* __restrict__ partial_s){
  __shared__ unsigned char Bl[128*528];
  __shared__ float sred[2][128];
  int tid = threadIdx.x;
  int chunk = blockIdx.x, rb = blockIdx.y;
  int w = tid>>6, lane = tid&63, q = lane>>4, rr = lane&15;
  int wi = w>>1, wj = w&1;
  long af[4][16];
  #pragma unroll
  for(int tr=0;tr<4;tr++)
    #pragma unroll
    for(int kc=0;kc<16;kc++){
      int row = rb*128 + wi*64 + tr*16 + rr;   // < RPAD always
      af[tr][kc] = *(const long*)(hs8 + (size_t)row*HD + kc*32 + q*8);
    }
  float sacc[16];
  #pragma unroll
  for(int i=0;i<16;i++) sacc[i]=0.f;
  int vc0 = chunk*2500, vc1 = vc0 + 2500;
  for(int vt=0; vt<20; vt++){
    int vbase = vc0 + vt*128;
    {
      int v = tid>>1, half = tid&1;
      int vg = vbase + v; if(vg > VV-1) vg = VV-1;
      const u32x4* s = (const u32x4*)(WoutT + (size_t)vg*HD + half*256);
      u32x4* d = (u32x4*)(Bl + v*528 + half*256);
      #pragma unroll
      for(int i=0;i<16;i++) d[i] = s[i];
    }
    __syncthreads();
    f32x4 acc[4][4];
    #pragma unroll
    for(int a=0;a<4;a++)
      #pragma unroll
      for(int b=0;b<4;b++){ acc[a][b][0]=0.f; acc[a][b][1]=0.f; acc[a][b][2]=0.f; acc[a][b][3]=0.f; }
    #pragma unroll
    for(int kc=0;kc<16;kc++){
      long bf[4];
      #pragma unroll
      for(int tc=0;tc<4;tc++)
        bf[tc] = *(const long*)(Bl + (wj*64 + tc*16 + rr)*528 + kc*32 + q*8);
      #pragma unroll
      for(int tr=0;tr<4;tr++)
        #pragma unroll
        for(int tc=0;tc<4;tc++)
          acc[tr][tc] = __builtin_amdgcn_mfma_f32_16x16x32_fp8_fp8(af[tr][kc], bf[tc], acc[tr][tc], 0, 0, 0);
    }
    #pragma unroll
    for(int tc=0;tc<4;tc++){
      int vg = vbase + wj*64 + tc*16 + rr;
      bool vok = vg < vc1;
      float boc = vok ? b_out[vg]*LOG2E : 0.f;
      #pragma unroll
      for(int tr=0;tr<4;tr++)
        #pragma unroll
        for(int reg=0;reg<4;reg++){
          float ex = __builtin_amdgcn_exp2f(__builtin_fmaf(acc[tr][tc][reg], LOG2E, boc));
          if(vok) sacc[tr*4+reg] += ex;
        }
    }
    __syncthreads();
  }
  #pragma unroll
  for(int i=0;i<16;i++){
    float v = sacc[i];
    v += __shfl_xor(v, 1, 64);
    v += __shfl_xor(v, 2, 64);
    v += __shfl_xor(v, 4, 64);
    v += __shfl_xor(v, 8, 64);
    sacc[i] = v;
  }
  if(rr == 0){
    #pragma unroll
    for(int tr=0;tr<4;tr++)
      #pragma unroll
      for(int reg=0;reg<4;reg++)
        sred[wj][wi*64 + tr*16 + q*4 + reg] = sacc[tr*4+reg];
  }
  __syncthreads();
  if(tid < 128){
    int row = rb*128 + tid;
    if(row < RTOT) partial_s[row*4 + chunk] = sred[0][tid] + sred[1][tid];
  }
}

// ---------------- K5: merged picked + loss. One wave per row; per-block partial
// loss summed and atomicAdd'ed into out[0] (zeroed by k_conv earlier in-stream).
__global__ __launch_bounds__(256) void k_pickedloss(const unsigned char* __restrict__ hs8,
    const unsigned char* __restrict__ WoutT, const float* __restrict__ b_out,
    const int* __restrict__ captions, const float* __restrict__ partial_s,
    float* __restrict__ out){
  int tid = threadIdx.x;
  int w = tid>>6, lane = tid&63;
  int R = blockIdx.x*4 + w;                 // 4080*4 = 16320 exact
  int t = R >> 6, n = R & 63;
  int y = captions[n*TT + t + 1];
  const unsigned int* hp = (const unsigned int*)(hs8 + (size_t)R*HD + lane*8);
  const unsigned int* wp = (const unsigned int*)(WoutT + (size_t)y*HD + lane*8);
  unsigned int hv0 = hp[0], hv1 = hp[1], wv0 = wp[0], wv1 = wp[1];
  float d = dot4_fp8(hv0, wv0) + dot4_fp8(hv1, wv1);
  d += __shfl_xor(d, 1, 64);
  d += __shfl_xor(d, 2, 64);
  d += __shfl_xor(d, 4, 64);
  d += __shfl_xor(d, 8, 64);
  d += __shfl_xor(d, 16, 64);
  d += __shfl_xor(d, 32, 64);
  __shared__ float red[4];
  if(lane == 0){
    float contrib = 0.f;
    if(y != 0){
      float picked = d + b_out[y];
      float s = partial_s[R*4] + partial_s[R*4+1] + partial_s[R*4+2] + partial_s[R*4+3];
      contrib = __logf(s) - picked;
    }
    red[w] = contrib;
  }
  __syncthreads();
  if(tid == 0){
    float v = (red[0]+red[1]+red[2]+red[3]) * (1.0f/64.0f);
    atomicAdd(out, v);
  }
}

extern "C" void kernel_launch(void* const* d_in, const int* in_sizes, int n_in,
                              void* d_out, int out_size, void* d_ws, size_t ws_size,
                              hipStream_t stream) {
  const float* feat    = (const float*)d_in[0];
  const float* W_proj  = (const float*)d_in[1];
  const float* b_proj  = (const float*)d_in[2];
  const float* W_embed = (const float*)d_in[3];
  const float* Wx      = (const float*)d_in[4];
  const float* Wh      = (const float*)d_in[5];
  const float* bvec    = (const float*)d_in[6];
  const float* W_out   = (const float*)d_in[7];
  const float* b_out   = (const float*)d_in[8];
  const int*   captions= (const int*)d_in[9];

  char* p = (char*)d_ws;
  unsigned short* WprojT = (unsigned short*)p;  p += 512*1280*2;
  unsigned short* WxT    = (unsigned short*)p;  p += 512*256*2;
  unsigned char*  Wh8S   = (unsigned char*)p;   p += 512*512;
  unsigned char*  WoutT  = (unsigned char*)p;   p += 10000*512;
  unsigned short* Wembb  = (unsigned short*)p;  p += 10000*256*2;
  unsigned short* featb  = (unsigned short*)p;  p += 64*1280*2;
  unsigned short* h0b    = (unsigned short*)p;  p += 64*512*2;
  unsigned short* xWk    = (unsigned short*)p;  p += TS*64*512*2;
  unsigned char*  hs8    = (unsigned char*)p;   p += RPAD*512;
  float* partial_s       = (float*)p;           p += RTOT*4*4;
  if((size_t)(p - (char*)d_ws) > ws_size) return;

  // fused conversions (+ zero out[0])
  k_conv<<<8090, 256, 0, stream>>>(W_proj, Wx, Wh, W_out, feat, W_embed,
                                   WprojT, WxT, Wh8S, WoutT, featb, Wembb,
                                   (float*)d_out);
  k_h0<<<8, 256, 0, stream>>>(featb, WprojT, b_proj, h0b);
  k_xw<<<dim3(8, TS), 256, 0, stream>>>(Wembb, WxT, bvec, captions, xWk);
  k_rnn<<<4, 512, 0, stream>>>(h0b, Wh8S, xWk, hs8);
  k_scores<<<dim3(4, 128), 256, 0, stream>>>(hs8, WoutT, b_out, partial_s);
  k_pickedloss<<<4080, 256, 0, stream>>>(hs8, WoutT, b_out, captions, partial_s, (float*)d_out);
}

// Round 10
// 551.716 us; speedup vs baseline: 1.1294x; 1.1294x over previous
//
#include <hip/hip_runtime.h>

// Problem dims
#define NS 64      // batch
#define TT 256     // caption length
#define TS 255     // RNN timesteps (T-1)
#define VV 10000   // vocab
#define DF 1280    // feature dim
#define WD 256     // word-embed dim
#define HD 512     // hidden dim
#define RTOT (TS*NS)   // 16320 output rows (r = t*64 + n)
#define RPAD 16384     // padded rows for hs

// 2*log2(e): tanh(x) = (e^{2x}-1)/(e^{2x}+1), e^{2x} = exp2(x * 2log2e)
#define TANH_SCALE 2.8853900817779268f
#define LOG2E 1.4426950408889634f

typedef __attribute__((ext_vector_type(4))) float f32x4;
typedef __attribute__((ext_vector_type(8))) short s16x8;
typedef __attribute__((ext_vector_type(4))) unsigned int u32x4;
typedef __attribute__((ext_vector_type(8))) int i32x8;

__device__ __forceinline__ unsigned short f2bf(float f){
  unsigned u; __builtin_memcpy(&u, &f, 4);
  u += 0x7FFFu + ((u >> 16) & 1u);            // RNE
  return (unsigned short)(u >> 16);
}
__device__ __forceinline__ float bf2f(unsigned short h){
  unsigned u = ((unsigned)h) << 16; float f; __builtin_memcpy(&f, &u, 4); return f;
}
__device__ __forceinline__ unsigned char f2fp8(float f){
  int p = __builtin_amdgcn_cvt_pk_fp8_f32(f, f, 0, false);  // OCP e4m3
  return (unsigned char)(p & 0xFF);
}
__device__ __forceinline__ float dot4_fp8(unsigned int a, unsigned int b){
  float d;
  d  = __builtin_amdgcn_cvt_f32_fp8(a, 0) * __builtin_amdgcn_cvt_f32_fp8(b, 0);
  d += __builtin_amdgcn_cvt_f32_fp8(a, 1) * __builtin_amdgcn_cvt_f32_fp8(b, 1);
  d += __builtin_amdgcn_cvt_f32_fp8(a, 2) * __builtin_amdgcn_cvt_f32_fp8(b, 2);
  d += __builtin_amdgcn_cvt_f32_fp8(a, 3) * __builtin_amdgcn_cvt_f32_fp8(b, 3);
  return d;
}
// MX-scaled MFMA, fp8 x fp8, unit scales -> exact fp8 GEMM at 2x rate (verified, absmax 0.0).
// LEDGER of k_rnn findings (its ~245us is the structural floor in this regime):
//  - trans ops (exp2/rcp) ~4-5x a VALU op; polynomial tanh is a wash (r4).
//  - compiler STREAMS MFMA operand arrays from L2 every step (VGPR 56/92); asm "+v" tuple
//    pin => scratch spill, 2.4x regression (r7). Do NOT pin tuples.
//  - bound: Wh re-stream 256KB/block/step at ~128B/cyc L2 port ~ 2000cyc ~ measured 2302.
//  - r9 two-port (LDS+L2) split FAILED +34us: LDS tuples need cat8 assembly (8 movs each)
//    and both ports' latencies serialize on the same wave's MFMA chain at 2 waves/SIMD.
__device__ __forceinline__ f32x4 mfma128(i32x8 a, i32x8 b, f32x4 c){
  return __builtin_amdgcn_mfma_scale_f32_16x16x128_f8f6f4(a, b, c, 0, 0, 0, 127, 0, 127);
}

// ---------------- fused K0: all weight/input conversions in ONE kernel.
// block ranges: [0,640) W_proj transpose | [640,768) Wx transpose | [768,1792) WhS (pre-scaled)
// [1792,6800) W_out transpose fp8 | [6800,6840) feat cvt x8 | [6840,8090) Wembb cvt x8
__device__ __forceinline__ void transpose_cvt_blk(const float* __restrict__ src,
    unsigned char* __restrict__ dst, int R, int C, int bx, int by, int fp8, int tid){
  __shared__ float tile[32][33];
  int r0 = bx*32, c0 = by*32;
  int tr = tid >> 5, tc = tid & 31;
  #pragma unroll
  for(int p=0;p<4;p++){
    int r = r0 + tr + p*8, c = c0 + tc;
    tile[tr + p*8][tc] = (r < R && c < C) ? src[r*C + c] : 0.f;
  }
  __syncthreads();
  #pragma unroll
  for(int p=0;p<4;p++){
    int oc = c0 + tr + p*8;
    int orow = r0 + tc;
    if(oc < C && orow < R){
      float v = tile[tc][tr + p*8];
      if(fp8) dst[oc*R + orow] = f2fp8(v);
      else ((unsigned short*)dst)[oc*R + orow] = f2bf(v);
    }
  }
}

__global__ __launch_bounds__(256) void k_conv(const float* __restrict__ W_proj,
    const float* __restrict__ Wx, const float* __restrict__ Wh,
    const float* __restrict__ W_out, const float* __restrict__ feat,
    const float* __restrict__ W_embed,
    unsigned short* __restrict__ WprojT, unsigned short* __restrict__ WxT,
    unsigned char* __restrict__ Wh8S, unsigned char* __restrict__ WoutT,
    unsigned short* __restrict__ featb, unsigned short* __restrict__ Wembb,
    float* __restrict__ out0){
  int b = blockIdx.x, tid = threadIdx.x;
  if(b == 0 && tid == 0) out0[0] = 0.f;       // zero loss accumulator (stream-ordered)
  if(b < 640){
    transpose_cvt_blk(W_proj, (unsigned char*)WprojT, 1280, 512, b%40, b/40, 0, tid);
  } else if(b < 768){
    int bb = b - 640;
    transpose_cvt_blk(Wx, (unsigned char*)WxT, 256, 512, bb%8, bb/8, 0, tid);
  } else if(b < 1792){
    int i = (b-768)*256 + tid;                 // Wh -> wave-order K=128-frag fp8, pre-scaled by 2log2e
    int blk = i>>11;
    int w = blk>>4, ct = (blk>>2)&3, kq = blk&3;
    int lane = (i>>5)&63, ib = i&31;
    int q = lane>>4, rrr = lane&15;
    int k = kq*128 + q*32 + ib;
    int j = w*64 + ct*16 + rrr;
    Wh8S[i] = f2fp8(Wh[k*HD + j] * TANH_SCALE);
  } else if(b < 6800){
    int bb = b - 1792;
    transpose_cvt_blk(W_out, WoutT, 512, 10000, bb%16, bb/16, 1, tid);
  } else if(b < 6840){
    int i = ((b-6800)*256 + tid)*8;            // 64*1280 = 40*2048
    f32x4 v0 = *(const f32x4*)(feat + i);
    f32x4 v1 = *(const f32x4*)(feat + i + 4);
    s16x8 o;
    #pragma unroll
    for(int j=0;j<4;j++){ o[j] = (short)f2bf(v0[j]); o[j+4] = (short)f2bf(v1[j]); }
    *(s16x8*)(featb + i) = o;
  } else {
    int i = ((b-6840)*256 + tid)*8;            // 10000*256 = 1250*2048
    f32x4 v0 = *(const f32x4*)(W_embed + i);
    f32x4 v1 = *(const f32x4*)(W_embed + i + 4);
    s16x8 o;
    #pragma unroll
    for(int j=0;j<4;j++){ o[j] = (short)f2bf(v0[j]); o[j+4] = (short)f2bf(v1[j]); }
    *(s16x8*)(Wembb + i) = o;
  }
}

// ---------------- K1: h0 = feat @ W_proj + b_proj  -> bf16 [64][512]
__global__ __launch_bounds__(256) void k_h0(const unsigned short* __restrict__ featb,
    const unsigned short* __restrict__ WprojT, const float* __restrict__ b_proj,
    unsigned short* __restrict__ h0b){
  __shared__ unsigned short Al[64*264];
  __shared__ unsigned short Bl[64*264];
  int tid = threadIdx.x, cb = blockIdx.x;
  int w = tid>>6, lane = tid&63, q = lane>>4, rr = lane&15;
  f32x4 acc[4];
  #pragma unroll
  for(int i=0;i<4;i++){ acc[i][0]=0.f; acc[i][1]=0.f; acc[i][2]=0.f; acc[i][3]=0.f; }
  for(int kb=0; kb<5; kb++){
    {
      int row = tid >> 2, part = tid & 3;
      const u32x4* s = (const u32x4*)(featb + row*DF + kb*256 + part*64);
      u32x4* d = (u32x4*)(Al + row*264 + part*64);
      #pragma unroll
      for(int i=0;i<8;i++) d[i] = s[i];
    }
    {
      int row = tid >> 2, part = tid & 3;
      int j = cb*64 + row;
      const u32x4* s = (const u32x4*)(WprojT + j*DF + kb*256 + part*64);
      u32x4* d = (u32x4*)(Bl + row*264 + part*64);
      #pragma unroll
      for(int i=0;i<8;i++) d[i] = s[i];
    }
    __syncthreads();
    #pragma unroll
    for(int kc=0;kc<8;kc++){
      s16x8 a = *(const s16x8*)(Al + (w*16 + rr)*264 + kc*32 + q*8);
      #pragma unroll
      for(int tc=0;tc<4;tc++){
        s16x8 bb = *(const s16x8*)(Bl + (tc*16 + rr)*264 + kc*32 + q*8);
        acc[tc] = __builtin_amdgcn_mfma_f32_16x16x32_bf16(a, bb, acc[tc], 0, 0, 0);
      }
    }
    __syncthreads();
  }
  #pragma unroll
  for(int tc=0;tc<4;tc++){
    #pragma unroll
    for(int reg=0;reg<4;reg++){
      int n = w*16 + q*4 + reg;
      int j = cb*64 + tc*16 + rr;
      h0b[n*HD + j] = f2bf(acc[tc][reg] + b_proj[j]);
    }
  }
}

// ---------------- K2: (xW + b) * 2log2e -> xWk, SWAPPED-K3 layout (pre-scaled for exp2).
// r10: 4 timesteps per block (grid 8x64) — WxT B-tile staged ONCE per block instead of
// per-t (saves ~49MB global re-reads + 75% of blocks). Inner per-t sequence unchanged.
__global__ __launch_bounds__(256) void k_xw(const unsigned short* __restrict__ Wembb,
    const unsigned short* __restrict__ WxT, const float* __restrict__ bvec,
    const int* __restrict__ captions, unsigned short* __restrict__ xWk){
  __shared__ unsigned short Al[64*264];
  __shared__ unsigned short Bl[64*264];
  int tid = threadIdx.x, cb = blockIdx.x, t0 = blockIdx.y*4;
  int w = tid>>6, lane = tid&63, q = lane>>4, rr = lane&15;
  {
    int row = tid >> 2, part = tid & 3;
    int j = cb*64 + row;
    const u32x4* s = (const u32x4*)(WxT + j*WD + part*64);
    u32x4* d = (u32x4*)(Bl + row*264 + part*64);
    #pragma unroll
    for(int i=0;i<8;i++) d[i] = s[i];
  }
  for(int tt=0; tt<4; tt++){
    int t = t0 + tt;
    {
      int row = tid >> 2, part = tid & 3;
      int idx = captions[row*TT + t];
      const u32x4* s = (const u32x4*)(Wembb + idx*WD + part*64);
      u32x4* d = (u32x4*)(Al + row*264 + part*64);
      #pragma unroll
      for(int i=0;i<8;i++) d[i] = s[i];
    }
    __syncthreads();
    f32x4 acc[4];
    #pragma unroll
    for(int i=0;i<4;i++){ acc[i][0]=0.f; acc[i][1]=0.f; acc[i][2]=0.f; acc[i][3]=0.f; }
    #pragma unroll
    for(int kc=0;kc<8;kc++){
      s16x8 a = *(const s16x8*)(Al + (w*16 + rr)*264 + kc*32 + q*8);
      #pragma unroll
      for(int tc=0;tc<4;tc++){
        s16x8 bb = *(const s16x8*)(Bl + (tc*16 + rr)*264 + kc*32 + q*8);
        acc[tc] = __builtin_amdgcn_mfma_f32_16x16x32_bf16(a, bb, acc[tc], 0, 0, 0);
      }
    }
    __syncthreads();                            // Al reads done; reuse Al as staging
    unsigned short* sx = (unsigned short*)Al;   // [4 chunks][1024] u16
    #pragma unroll
    for(int tc=0;tc<4;tc++){
      int j = cb*64 + tc*16 + rr;
      float bo = bvec[j];
      #pragma unroll
      for(int reg=0;reg<4;reg++)
        sx[w*1024 + (rr>>2)*256 + (q*4+reg)*16 + tc*4 + (rr&3)]
          = f2bf((acc[tc][reg] + bo) * TANH_SCALE);
    }
    __syncthreads();
    {
      int o = tid*16;                           // u16 units, 0..4095
      int blk = o >> 10, inner = o & 1023;
      unsigned short* dst = xWk + (((size_t)t*4 + blk)*8 + cb)*1024 + inner;
      const u32x4* s = (const u32x4*)(sx + o);
      *(u32x4*)(dst)     = s[0];
      *(u32x4*)(dst + 8) = s[1];
    }
    __syncthreads();                            // copy-out done before next A-stage
  }
}

// ---------------- K3: RNN scan — EXACT round-6 proven body (244.6 us, VGPR 56, Occ 0.74).
// 16 waves x 32-j strips, wb[8] streamed from L2 (all residency attempts fail — ledger).
__global__ __launch_bounds__(1024, 1) void k_rnn(const unsigned short* __restrict__ h0b,
    const unsigned char* __restrict__ Wh8S, const unsigned short* __restrict__ xWk,
    unsigned char* __restrict__ hs8){
  __shared__ unsigned char hbuf[2][16*560];    // fp8 h, [n][j] stride 560
  int tid = threadIdx.x, w = tid>>6, lane = tid&63, q = lane>>4, rr = lane&15;
  int n0 = blockIdx.x * 16;
  int j0 = w * 32;
  i32x8 wb[8];                                 // 2 ct tiles x 4 kq
  #pragma unroll
  for(int c=0;c<2;c++)
    #pragma unroll
    for(int kq=0;kq<4;kq++)
      wb[c*4+kq] = *(const i32x8*)(Wh8S + (size_t)((w*2 + c)*4 + kq)*2048 + lane*32);
  {
    int s = tid>>6, c0 = (tid&63)*8;
    #pragma unroll
    for(int i=0;i<8;i++)
      hbuf[0][s*560 + c0 + i] = f2fp8(bf2f(h0b[(n0+s)*HD + c0 + i]));
  }
  __syncthreads();
  int scp = tid>>6, scc = (tid&63)*8;
  const unsigned short* xp = xWk + (((size_t)blockIdx.x)*8 + (w>>1))*1024
                                 + q*256 + rr*16 + (w&1)*8;
  unsigned short xs[8];
  *(u32x4*)(xs) = *(const u32x4*)(xp);
  for(int t=0; t<TS; t++){
    const unsigned char* hb = hbuf[t&1];
    unsigned char*       hn = hbuf[(t&1)^1];
    if(t)
      *(unsigned long*)(hs8 + (size_t)((t-1)*NS + n0 + scp)*HD + scc)
        = *(const unsigned long*)(hb + scp*560 + scc);
    f32x4 acc[2];                               // C-operand = pre-scaled xW (swapped layout)
    #pragma unroll
    for(int c=0;c<2;c++)
      #pragma unroll
      for(int reg=0;reg<4;reg++)
        acc[c][reg] = bf2f(xs[c*4+reg]);
    unsigned short xn[8];                       // prefetch next step's xW
    *(u32x4*)(xn) = *(const u32x4*)(xp + 32768);
    i32x8 af[4];
    #pragma unroll
    for(int kq=0;kq<4;kq++)
      af[kq] = *(const i32x8*)(hb + rr*560 + kq*128 + q*32);
    #pragma unroll
    for(int c=0;c<2;c++)
      #pragma unroll
      for(int kq=0;kq<4;kq++)
        acc[c] = mfma128(wb[c*4+kq], af[kq], acc[c]);   // SWAPPED: out = (h*Wh)^T
    #pragma unroll
    for(int c=0;c<2;c++){
      float h[4];
      #pragma unroll
      for(int reg=0;reg<4;reg++){
        float e2 = __builtin_amdgcn_exp2f(acc[c][reg]);              // acc pre-scaled by 2log2e
        h[reg] = __builtin_fmaf(-2.f, __builtin_amdgcn_rcpf(e2 + 1.f), 1.f);  // tanh
      }
      int pk = __builtin_amdgcn_cvt_pk_fp8_f32(h[0], h[1], 0, false);
      pk     = __builtin_amdgcn_cvt_pk_fp8_f32(h[2], h[3], pk, true);
      *(unsigned int*)(hn + rr*560 + j0 + c*16 + q*4) = (unsigned)pk;
    }
    __syncthreads();
    xp += 32768;
    *(u32x4*)(xs) = *(u32x4*)(xn);
  }
  *(unsigned long*)(hs8 + (size_t)((TS-1)*NS + n0 + scp)*HD + scc)
    = *(const unsigned long*)(hbuf[TS&1] + scp*560 + scc);
}

// ---------------- K4: fused scores GEMM + sumexp partials — FROZEN round-5 proven config
// (256 thr, dim3(4,128)). 512-thr/256-row variant spills (VGPR capped at 128 = af size).
__global__ __launch_bounds__(256, 2) void k_scores(const unsigned char* __restrict__ hs8,
    const unsigned char* __restrict__ WoutT, const float* __restrict__ b_out,
    float* __restrict__ partial_s){
  __shared__ unsigned char Bl[128*528];
  __shared__ float sred[2][128];
  int tid = threadIdx.x;
  int chunk = blockIdx.x, rb = blockIdx.y;
  int w = tid>>6, lane = tid&63, q = lane>>4, rr = lane&15;
  int wi = w>>1, wj = w&1;
  long af[4][16];
  #pragma unroll
  for(int tr=0;tr<4;tr++)
    #pragma unroll
    for(int kc=0;kc<16;kc++){
      int row = rb*128 + wi*64 + tr*16 + rr;   // < RPAD always
      af[tr][kc] = *(const long*)(hs8 + (size_t)row*HD + kc*32 + q*8);
    }
  float sacc[16];
  #pragma unroll
  for(int i=0;i<16;i++) sacc[i]=0.f;
  int vc0 = chunk*2500, vc1 = vc0 + 2500;
  for(int vt=0; vt<20; vt++){
    int vbase = vc0 + vt*128;
    {
      int v = tid>>1, half = tid&1;
      int vg = vbase + v; if(vg > VV-1) vg = VV-1;
      const u32x4* s = (const u32x4*)(WoutT + (size_t)vg*HD + half*256);
      u32x4* d = (u32x4*)(Bl + v*528 + half*256);
      #pragma unroll
      for(int i=0;i<16;i++) d[i] = s[i];
    }
    __syncthreads();
    f32x4 acc[4][4];
    #pragma unroll
    for(int a=0;a<4;a++)
      #pragma unroll
      for(int b=0;b<4;b++){ acc[a][b][0]=0.f; acc[a][b][1]=0.f; acc[a][b][2]=0.f; acc[a][b][3]=0.f; }
    #pragma unroll
    for(int kc=0;kc<16;kc++){
      long bf[4];
      #pragma unroll
      for(int tc=0;tc<4;tc++)
        bf[tc] = *(const long*)(Bl + (wj*64 + tc*16 + rr)*528 + kc*32 + q*8);
      #pragma unroll
      for(int tr=0;tr<4;tr++)
        #pragma unroll
        for(int tc=0;tc<4;tc++)
          acc[tr][tc] = __builtin_amdgcn_mfma_f32_16x16x32_fp8_fp8(af[tr][kc], bf[tc], acc[tr][tc], 0, 0, 0);
    }
    #pragma unroll
    for(int tc=0;tc<4;tc++){
      int vg = vbase + wj*64 + tc*16 + rr;
      bool vok = vg < vc1;
      float boc = vok ? b_out[vg]*LOG2E : 0.f;
      #pragma unroll
      for(int tr=0;tr<4;tr++)
        #pragma unroll
        for(int reg=0;reg<4;reg++){
          float ex = __builtin_amdgcn_exp2f(__builtin_fmaf(acc[tr][tc][reg], LOG2E, boc));
          if(vok) sacc[tr*4+reg] += ex;
        }
    }
    __syncthreads();
  }
  #pragma unroll
  for(int i=0;i<16;i++){
    float v = sacc[i];
    v += __shfl_xor(v, 1, 64);
    v += __shfl_xor(v, 2, 64);
    v += __shfl_xor(v, 4, 64);
    v += __shfl_xor(v, 8, 64);
    sacc[i] = v;
  }
  if(rr == 0){
    #pragma unroll
    for(int tr=0;tr<4;tr++)
      #pragma unroll
      for(int reg=0;reg<4;reg++)
        sred[wj][wi*64 + tr*16 + q*4 + reg] = sacc[tr*4+reg];
  }
  __syncthreads();
  if(tid < 128){
    int row = rb*128 + tid;
    if(row < RTOT) partial_s[row*4 + chunk] = sred[0][tid] + sred[1][tid];
  }
}

// ---------------- K5: merged picked + loss. r10: 64 rows/block (16 per wave, serial),
// 255 blocks -> 255 same-address atomics instead of 4080 (atomic serialization was a
// ~13us tail on the last kernel). 16 independent gathers per wave pipeline under #unroll.
__global__ __launch_bounds__(256) void k_pickedloss(const unsigned char* __restrict__ hs8,
    const unsigned char* __restrict__ WoutT, const float* __restrict__ b_out,
    const int* __restrict__ captions, const float* __restrict__ partial_s,
    float* __restrict__ out){
  int tid = threadIdx.x;
  int w = tid>>6, lane = tid&63;
  float contrib = 0.f;
  #pragma unroll 4
  for(int i=0;i<16;i++){
    int R = blockIdx.x*64 + w*16 + i;         // 255*64 = 16320 exact
    int t = R >> 6, n = R & 63;
    int y = captions[n*TT + t + 1];
    const unsigned int* hp = (const unsigned int*)(hs8 + (size_t)R*HD + lane*8);
    const unsigned int* wp = (const unsigned int*)(WoutT + (size_t)y*HD + lane*8);
    float d = dot4_fp8(hp[0], wp[0]) + dot4_fp8(hp[1], wp[1]);
    d += __shfl_xor(d, 1, 64);
    d += __shfl_xor(d, 2, 64);
    d += __shfl_xor(d, 4, 64);
    d += __shfl_xor(d, 8, 64);
    d += __shfl_xor(d, 16, 64);
    d += __shfl_xor(d, 32, 64);
    if(lane == 0 && y != 0){
      float picked = d + b_out[y];
      float s = partial_s[R*4] + partial_s[R*4+1] + partial_s[R*4+2] + partial_s[R*4+3];
      contrib += __logf(s) - picked;
    }
  }
  __shared__ float red[4];
  if(lane == 0) red[w] = contrib;
  __syncthreads();
  if(tid == 0){
    float v = (red[0]+red[1]+red[2]+red[3]) * (1.0f/64.0f);
    atomicAdd(out, v);
  }
}

extern "C" void kernel_launch(void* const* d_in, const int* in_sizes, int n_in,
                              void* d_out, int out_size, void* d_ws, size_t ws_size,
                              hipStream_t stream) {
  const float* feat    = (const float*)d_in[0];
  const float* W_proj  = (const float*)d_in[1];
  const float* b_proj  = (const float*)d_in[2];
  const float* W_embed = (const float*)d_in[3];
  const float* Wx      = (const float*)d_in[4];
  const float* Wh      = (const float*)d_in[5];
  const float* bvec    = (const float*)d_in[6];
  const float* W_out   = (const float*)d_in[7];
  const float* b_out   = (const float*)d_in[8];
  const int*   captions= (const int*)d_in[9];

  char* p = (char*)d_ws;
  unsigned short* WprojT = (unsigned short*)p;  p += 512*1280*2;
  unsigned short* WxT    = (unsigned short*)p;  p += 512*256*2;
  unsigned char*  Wh8S   = (unsigned char*)p;   p += 512*512;
  unsigned char*  WoutT  = (unsigned char*)p;   p += 10000*512;
  unsigned short* Wembb  = (unsigned short*)p;  p += 10000*256*2;
  unsigned short* featb  = (unsigned short*)p;  p += 64*1280*2;
  unsigned short* h0b    = (unsigned short*)p;  p += 64*512*2;
  unsigned short* xWk    = (unsigned short*)p;  p += TS*64*512*2;
  unsigned char*  hs8    = (unsigned char*)p;   p += RPAD*512;
  float* partial_s       = (float*)p;           p += RTOT*4*4;
  if((size_t)(p - (char*)d_ws) > ws_size) return;

  // fused conversions (+ zero out[0])
  k_conv<<<8090, 256, 0, stream>>>(W_proj, Wx, Wh, W_out, feat, W_embed,
                                   WprojT, WxT, Wh8S, WoutT, featb, Wembb,
                                   (float*)d_out);
  k_h0<<<8, 256, 0, stream>>>(featb, WprojT, b_proj, h0b);
  k_xw<<<dim3(8, 64), 256, 0, stream>>>(Wembb, WxT, bvec, captions, xWk);
  k_rnn<<<4, 1024, 0, stream>>>(h0b, Wh8S, xWk, hs8);
  k_scores<<<dim3(4, 128), 256, 0, stream>>>(hs8, WoutT, b_out, partial_s);
  k_pickedloss<<<255, 256, 0, stream>>>(hs8, WoutT, b_out, captions, partial_s, (float*)d_out);
}